// Round 5
// baseline (543.226 us; speedup 1.0000x reference)
//
#include <hip/hip_runtime.h>
#include <hip/hip_bf16.h>

// Static problem config (BEVFormer-base-ish, 50x50 BEV grid)
#define L_TOT   19560
#define NQ      2500
#define NCAMS   6
#define M_VAL   (NCAMS * L_TOT)   // 117360

typedef __attribute__((ext_vector_type(8))) short short8;
typedef __attribute__((ext_vector_type(4))) float f32x4;

__device__ __forceinline__ unsigned short f2bf(float x) {
  __hip_bfloat16 h = __float2bfloat16(x);
  return *reinterpret_cast<unsigned short*>(&h);
}
__device__ __forceinline__ unsigned int pack2bf(float lo, float hi) {
  return (unsigned int)f2bf(lo) | ((unsigned int)f2bf(hi) << 16);
}
__device__ __forceinline__ float bf_lo(unsigned int u) {
  return __uint_as_float(u << 16);
}
__device__ __forceinline__ float bf_hi(unsigned int u) {
  return __uint_as_float(u & 0xffff0000u);
}

// ---------------------------------------------------------------------------
// bev_mask canonicalizer (bool may arrive as u8 / i32 / f32) + per-query 1/cnt
// + concatenated bias [b_off(512); b_attn(256)]
// ---------------------------------------------------------------------------
__global__ void canon_mask_kernel(const void* __restrict__ in,
                                  unsigned char* __restrict__ outm,
                                  float* __restrict__ invcnt,
                                  const float* __restrict__ b_off,
                                  const float* __restrict__ b_attn,
                                  float* __restrict__ bcat) {
  __shared__ int notI, notF;
  if (threadIdx.x == 0) { notI = 0; notF = 0; }
  __syncthreads();
  const unsigned int* w = (const unsigned int*)in;
  for (int i = threadIdx.x; i < 3750; i += 256) {
    unsigned int x = w[i];
    if (x != 0u && x != 1u)          atomicOr(&notI, 1);
    if (x != 0u && x != 0x3f800000u) atomicOr(&notF, 1);
  }
  __syncthreads();
  int mode = (notI == 0) ? 1 : ((notF == 0) ? 2 : 0); // 1=i32, 2=f32, 0=u8
  for (int i = threadIdx.x; i < NCAMS * NQ; i += 256) {
    unsigned char v;
    if (mode == 1)      v = (unsigned char)(w[i] != 0u);
    else if (mode == 2) v = (unsigned char)(((const float*)in)[i] != 0.0f);
    else                v = (unsigned char)(((const unsigned char*)in)[i] != 0);
    outm[i] = v;
  }
  __syncthreads();
  for (int q = threadIdx.x; q < NQ; q += 256) {
    int cnt = 0;
#pragma unroll
    for (int c = 0; c < NCAMS; ++c) cnt += outm[c * NQ + q];
    invcnt[q] = 1.f / (float)max(cnt, 1);
  }
  for (int i = threadIdx.x; i < 768; i += 256)
    bcat[i] = (i < 512) ? b_off[i] : b_attn[i - 512];
}

// ---------------------------------------------------------------------------
// Convert weights to bf16: W_value -> o0[65536]; [W_off;W_attn] -> o1[196608];
// W_out -> o2[65536].
// ---------------------------------------------------------------------------
__global__ void cvt_weights_kernel(const float* __restrict__ wv,
                                   const float* __restrict__ woff,
                                   const float* __restrict__ wattn,
                                   const float* __restrict__ wout,
                                   unsigned short* __restrict__ o0,
                                   unsigned short* __restrict__ o1,
                                   unsigned short* __restrict__ o2) {
  int i = blockIdx.x * 256 + threadIdx.x;
  if (i < 65536)        o0[i] = f2bf(wv[i]);
  else if (i < 196608)  o1[i - 65536] = f2bf(woff[i - 65536]);
  else if (i < 262144)  o1[131072 + (i - 196608)] = f2bf(wattn[i - 196608]);
  else if (i < 327680)  o2[i - 262144] = f2bf(wout[i - 262144]);
}

// ---------------------------------------------------------------------------
// LDS-resident-W MFMA GEMM, barrier-free K-loop:
//   C[m, ch] = sum_k bf16(scale[m]*(A[m,k]+A2[m,k])) * W[ch,k] + bias[ch]
//              (+ R[m,ch])
// Block = 4 waves, 256 rows (wave w: rows m0+w*64..+64, 4 tiles of 16).
// blockIdx.y selects a 128-channel half of W: 128x256 bf16 = 64 KB LDS,
// stored FRAGMENT-MAJOR (Ws[ct][kt][lane][8]) so the MFMA-fragment read is
// the canonical conflict-free lane*16B ds_read_b128. One __syncthreads after
// staging; the row loop has NO barriers -> global A loads (16 independent
// dwordx4 per tile) pipeline freely across tiles.
// A-operand = W (m=channel), B-operand = A-row (n=row); D: row=fr, ch=fg*4+r.
// ---------------------------------------------------------------------------
template <bool BF16_OUT, bool HAS_A2, bool HAS_RES, bool HAS_SCALE>
__global__ __launch_bounds__(256, 2) void gemm_ldsw_kernel(
    const float* __restrict__ A, const float* __restrict__ A2,
    const unsigned short* __restrict__ Wbf, const float* __restrict__ bias,
    const float* __restrict__ R, const float* __restrict__ rowscale,
    void* __restrict__ Cv, int M, int N) {
  __shared__ unsigned short Ws[8][8][64][8];  // [ct][kt][lane][8] = 64 KB
  const int tid = threadIdx.x;
  const int wave = tid >> 6;
  const int lane = tid & 63;
  const int fr = lane & 15;
  const int fg = lane >> 4;
  const int m0 = blockIdx.x * 256;
  const int nb = blockIdx.y * 128;

  // ---- stage W half, fragment-major ----
#pragma unroll
  for (int i = 0; i < 16; ++i) {
    const int flat = i * 256 + tid;
    const int l = flat & 63;
    const int f = flat >> 6;          // 0..63
    const int kt = f & 7, ct = f >> 3;
    const int ch = nb + ct * 16 + (l & 15);
    const int k0 = kt * 32 + (l >> 4) * 8;
    *(uint4*)(&Ws[ct][kt][l][0]) =
        *(const uint4*)(Wbf + (size_t)ch * 256 + k0);
  }
  __syncthreads();

  // ---- stream rows; no barriers from here on ----
  const int wrow = m0 + wave * 64;
#pragma unroll 2
  for (int it = 0; it < 4; ++it) {
    const int rowbase = wrow + it * 16;
    const int rc = min(rowbase + fr, M - 1);
    const float* ap = A + (size_t)rc * 256 + fg * 8;
    const float* a2p = HAS_A2 ? (A2 + (size_t)rc * 256 + fg * 8) : nullptr;
    const float scale = HAS_SCALE ? rowscale[rc] : 1.f;

    float4 s0[8], s1[8];
#pragma unroll
    for (int kt = 0; kt < 8; ++kt) {
      s0[kt] = *(const float4*)(ap + kt * 32);
      s1[kt] = *(const float4*)(ap + kt * 32 + 4);
    }
    if (HAS_A2) {
#pragma unroll
      for (int kt = 0; kt < 8; ++kt) {
        const float4 t0 = *(const float4*)(a2p + kt * 32);
        const float4 t1 = *(const float4*)(a2p + kt * 32 + 4);
        s0[kt].x += t0.x; s0[kt].y += t0.y; s0[kt].z += t0.z; s0[kt].w += t0.w;
        s1[kt].x += t1.x; s1[kt].y += t1.y; s1[kt].z += t1.z; s1[kt].w += t1.w;
      }
    }
    if (HAS_SCALE) {
#pragma unroll
      for (int kt = 0; kt < 8; ++kt) {
        s0[kt].x *= scale; s0[kt].y *= scale;
        s0[kt].z *= scale; s0[kt].w *= scale;
        s1[kt].x *= scale; s1[kt].y *= scale;
        s1[kt].z *= scale; s1[kt].w *= scale;
      }
    }
    short8 afr[8];
#pragma unroll
    for (int kt = 0; kt < 8; ++kt) {
      uint4 u;
      u.x = pack2bf(s0[kt].x, s0[kt].y);
      u.y = pack2bf(s0[kt].z, s0[kt].w);
      u.z = pack2bf(s1[kt].x, s1[kt].y);
      u.w = pack2bf(s1[kt].z, s1[kt].w);
      afr[kt] = *(const short8*)&u;
    }

    f32x4 acc[8] = {};
#pragma unroll
    for (int kt = 0; kt < 8; ++kt)
#pragma unroll
      for (int ct = 0; ct < 8; ++ct)
        acc[ct] = __builtin_amdgcn_mfma_f32_16x16x32_bf16(
            *(const short8*)&Ws[ct][kt][lane][0], afr[kt], acc[ct], 0, 0, 0);

    // epilogue: D -> data row = fr, channel = fg*4 + reg
    const int m = rowbase + fr;
    if (m < M) {
#pragma unroll
      for (int ct = 0; ct < 8; ++ct) {
        const int ch = nb + ct * 16 + fg * 4;
        float o[4];
#pragma unroll
        for (int r = 0; r < 4; ++r) o[r] = acc[ct][r] + bias[ch + r];
        if (HAS_RES) {
          const float4 r4 = *(const float4*)&R[(size_t)m * N + ch];
          o[0] += r4.x; o[1] += r4.y; o[2] += r4.z; o[3] += r4.w;
        }
        if (BF16_OUT) {
          ushort4 u;
          u.x = f2bf(o[0]); u.y = f2bf(o[1]);
          u.z = f2bf(o[2]); u.w = f2bf(o[3]);
          *(ushort4*)((unsigned short*)Cv + (size_t)m * N + ch) = u;
        } else {
          float4 of; of.x = o[0]; of.y = o[1]; of.z = o[2]; of.w = o[3];
          *(float4*)((float*)Cv + (size_t)m * N + ch) = of;
        }
      }
    }
  }
}

// ---------------------------------------------------------------------------
// Sampler: one block per (cam, query) pair; 128 threads, 2 channels each.
// offlog: [q][768] = [off(512) | logits(256)].
// ---------------------------------------------------------------------------
__global__ __launch_bounds__(128) void sampler2_kernel(
    const unsigned short* __restrict__ v, const float* __restrict__ offlog,
    const float* __restrict__ ref, const unsigned char* __restrict__ mask,
    float* __restrict__ slots) {
  const int pair = blockIdx.x;                 // c * NQ + q
  if (!mask[pair]) return;
  const int c = pair / NQ;
  const int q = pair - c * NQ;
  const int tt = threadIdx.x;                  // 0..127

  __shared__ float sx[256], sy[256], sw[256];
  {
    const float Wl[4] = {160.f, 80.f, 40.f, 20.f};
    const float Hl[4] = {92.f, 46.f, 23.f, 12.f};
#pragma unroll
    for (int rep = 0; rep < 2; ++rep) {
      const int combo = tt + rep * 128;        // (h,l,p): h=combo>>5
      const int l = (combo >> 3) & 3;
      const int p = combo & 7;
      const int z = p & 3;                     // NP//NZ x NZ reshape
      const float2 rz = ((const float2*)ref)[q * 4 + z];
      const float2 o2 = ((const float2*)offlog)[(size_t)q * 384 + combo];
      sx[combo] = rz.x * Wl[l] + o2.x - 0.5f;
      sy[combo] = rz.y * Hl[l] + o2.y - 0.5f;
      float lg = offlog[(size_t)q * 768 + 512 + combo];
      float mx = lg;
      for (int s = 16; s; s >>= 1) mx = fmaxf(mx, __shfl_xor(mx, s, 32));
      float e = __expf(lg - mx);
      float sm = e;
      for (int s = 16; s; s >>= 1) sm += __shfl_xor(sm, s, 32);
      sw[combo] = e / sm;
    }
  }
  __syncthreads();

  const int WW[4] = {160, 80, 40, 20};
  const int HH[4] = {92, 46, 23, 12};
  const int LS[4] = {0, 14720, 18400, 19320};

  const unsigned int* vc =
      (const unsigned int*)(v + (size_t)c * (L_TOT * 256)) + tt;
  const int cbase = (tt >> 4) * 32;
  float acc0 = 0.f, acc1 = 0.f;

#pragma unroll 8
  for (int s = 0; s < 32; ++s) {
    const int lvl = s >> 3;
    const int combo = cbase + s;
    const float x = sx[combo], y = sy[combo], w = sw[combo];
    const float fx0 = floorf(x), fy0 = floorf(y);
    const float fx = x - fx0, fy = y - fy0;
    const int x0 = (int)fx0, y0 = (int)fy0;
    const int Wi = WW[lvl], Hi = HH[lvl];
    const int x0c = min(max(x0, 0), Wi - 1);
    const int x1c = min(max(x0 + 1, 0), Wi - 1);
    const int y0c = min(max(y0, 0), Hi - 1);
    const int y1c = min(max(y0 + 1, 0), Hi - 1);
    const float vx0 = (x0 >= 0 && x0 < Wi) ? 1.f : 0.f;
    const float vx1 = (x0 + 1 >= 0 && x0 + 1 < Wi) ? 1.f : 0.f;
    const float vy0 = (y0 >= 0 && y0 < Hi) ? 1.f : 0.f;
    const float vy1 = (y0 + 1 >= 0 && y0 + 1 < Hi) ? 1.f : 0.f;
    const unsigned int* vl = vc + (size_t)LS[lvl] * 128;
    const unsigned int u00 = vl[(y0c * Wi + x0c) * 128];
    const unsigned int u01 = vl[(y0c * Wi + x1c) * 128];
    const unsigned int u10 = vl[(y1c * Wi + x0c) * 128];
    const unsigned int u11 = vl[(y1c * Wi + x1c) * 128];
    const float w00 = (1.f - fx) * (1.f - fy) * vx0 * vy0 * w;
    const float w01 = fx * (1.f - fy) * vx1 * vy0 * w;
    const float w10 = (1.f - fx) * fy * vx0 * vy1 * w;
    const float w11 = fx * fy * vx1 * vy1 * w;
    acc0 += w00 * bf_lo(u00) + w01 * bf_lo(u01) +
            w10 * bf_lo(u10) + w11 * bf_lo(u11);
    acc1 += w00 * bf_hi(u00) + w01 * bf_hi(u01) +
            w10 * bf_hi(u10) + w11 * bf_hi(u11);
  }
  atomicAdd(&slots[q * 256 + tt * 2], acc0);
  atomicAdd(&slots[q * 256 + tt * 2 + 1], acc1);
}

// ---------------------------------------------------------------------------
extern "C" void kernel_launch(void* const* d_in, const int* in_sizes, int n_in,
                              void* d_out, int out_size, void* d_ws,
                              size_t ws_size, hipStream_t stream) {
  const float* query  = (const float*)d_in[0];
  // d_in[1] = key : unused by the reference forward
  const float* value  = (const float*)d_in[2];
  const float* qpos   = (const float*)d_in[3];
  const float* refpts = (const float*)d_in[4];
  const void*  bmask  = d_in[5];
  const float* W_value = (const float*)d_in[8];
  const float* b_value = (const float*)d_in[9];
  const float* W_off   = (const float*)d_in[10];
  const float* b_off   = (const float*)d_in[11];
  const float* W_attn  = (const float*)d_in[12];
  const float* b_attn  = (const float*)d_in[13];
  const float* W_out   = (const float*)d_in[14];
  const float* b_out   = (const float*)d_in[15];
  float* out = (float*)d_out;

  // workspace layout (~71 MB)
  unsigned short* ws_v = (unsigned short*)d_ws;                    // M_VAL*256 bf16
  unsigned short* ws_wv   = ws_v + (size_t)M_VAL * 256;            // 65536
  unsigned short* ws_wq   = ws_wv + 65536;                         // 196608
  unsigned short* ws_wout = ws_wq + 196608;                        // 65536
  float* ws_offlog = (float*)(ws_wout + 65536);                    // NQ*768
  float* ws_slots  = ws_offlog + (size_t)NQ * 768;                 // NQ*256
  float* ws_invcnt = ws_slots + (size_t)NQ * 256;                  // NQ
  float* ws_bcat   = ws_invcnt + NQ;                               // 768
  unsigned char* ws_mask = (unsigned char*)(ws_bcat + 768);        // NCAMS*NQ

  canon_mask_kernel<<<1, 256, 0, stream>>>(bmask, ws_mask, ws_invcnt,
                                           b_off, b_attn, ws_bcat);
  cvt_weights_kernel<<<1280, 256, 0, stream>>>(
      W_value, W_off, W_attn, W_out, ws_wv, ws_wq, ws_wout);

  // [off | logits] = (q+qpos) @ [W_off;W_attn]^T + bcat   (2500 x 768)
  gemm_ldsw_kernel<false, true, false, false><<<dim3(10, 6), 256, 0, stream>>>(
      query, qpos, ws_wq, ws_bcat, nullptr, nullptr, (void*)ws_offlog,
      NQ, 768);

  // v = value @ W_value^T + b_value   (117360 x 256), bf16 out
  gemm_ldsw_kernel<true, false, false, false><<<dim3(459, 2), 256, 0, stream>>>(
      value, nullptr, ws_wv, b_value, nullptr, nullptr, (void*)ws_v,
      M_VAL, 256);

  hipMemsetAsync(ws_slots, 0, (size_t)NQ * 256 * sizeof(float), stream);
  sampler2_kernel<<<NCAMS * NQ, 128, 0, stream>>>(
      ws_v, ws_offlog, refpts, ws_mask, ws_slots);

  // out = (slots/cnt) @ W_out^T + b_out + query   (2500 x 256)
  gemm_ldsw_kernel<false, false, true, true><<<dim3(10, 2), 256, 0, stream>>>(
      ws_slots, nullptr, ws_wout, b_out, query, ws_invcnt, (void*)out,
      NQ, 256);
}

// Round 6
// 383.450 us; speedup vs baseline: 1.4167x; 1.4167x over previous
//
#include <hip/hip_runtime.h>
#include <hip/hip_bf16.h>

// Static problem config (BEVFormer-base-ish, 50x50 BEV grid)
#define L_TOT   19560
#define NQ      2500
#define NCAMS   6
#define M_VAL   (NCAMS * L_TOT)   // 117360

typedef __attribute__((ext_vector_type(8))) short short8;
typedef __attribute__((ext_vector_type(4))) float f32x4;

__device__ __forceinline__ unsigned short f2bf(float x) {
  __hip_bfloat16 h = __float2bfloat16(x);
  return *reinterpret_cast<unsigned short*>(&h);
}
__device__ __forceinline__ unsigned int pack2bf(float lo, float hi) {
  return (unsigned int)f2bf(lo) | ((unsigned int)f2bf(hi) << 16);
}
__device__ __forceinline__ float bf_lo(unsigned int u) {
  return __uint_as_float(u << 16);
}
__device__ __forceinline__ float bf_hi(unsigned int u) {
  return __uint_as_float(u & 0xffff0000u);
}

__device__ __forceinline__ unsigned char canon_bool(const void* in, int i,
                                                    int mode) {
  if (mode == 1) return (unsigned char)(((const unsigned int*)in)[i] != 0u);
  if (mode == 2) return (unsigned char)(((const float*)in)[i] != 0.0f);
  return (unsigned char)(((const unsigned char*)in)[i] != 0);
}

// ---------------------------------------------------------------------------
// Parallel bev_mask canonicalizer (bool may arrive as u8 / i32 / f32).
// Every block redundantly sniffs the dtype (3750 words, L2-hot), then:
//  - all 60 blocks: canonical u8 mask slice
//  - blocks 0..9:   invcnt slice (250 q each) straight from input
//  - block 10:      bcat = [b_off(512); b_attn(256)]
// ---------------------------------------------------------------------------
__global__ void canon_mask_kernel(const void* __restrict__ in,
                                  unsigned char* __restrict__ outm,
                                  float* __restrict__ invcnt,
                                  const float* __restrict__ b_off,
                                  const float* __restrict__ b_attn,
                                  float* __restrict__ bcat) {
  __shared__ int notI, notF;
  if (threadIdx.x == 0) { notI = 0; notF = 0; }
  __syncthreads();
  const unsigned int* w = (const unsigned int*)in;
  for (int i = threadIdx.x; i < 3750; i += 256) {
    unsigned int x = w[i];
    if (x != 0u && x != 1u)          atomicOr(&notI, 1);
    if (x != 0u && x != 0x3f800000u) atomicOr(&notF, 1);
  }
  __syncthreads();
  const int mode = (notI == 0) ? 1 : ((notF == 0) ? 2 : 0);

  const int i = blockIdx.x * 256 + threadIdx.x;
  if (i < NCAMS * NQ) outm[i] = canon_bool(in, i, mode);

  if (blockIdx.x < 10) {
    const int q0 = blockIdx.x * 250;
    for (int q = q0 + threadIdx.x; q < q0 + 250; q += 256) {
      int cnt = 0;
#pragma unroll
      for (int c = 0; c < NCAMS; ++c) cnt += canon_bool(in, c * NQ + q, mode);
      invcnt[q] = 1.f / (float)max(cnt, 1);
    }
  } else if (blockIdx.x == 10) {
    for (int j = threadIdx.x; j < 768; j += 256)
      bcat[j] = (j < 512) ? b_off[j] : b_attn[j - 512];
  }
}

// ---------------------------------------------------------------------------
// Convert weights to bf16: W_value -> o0[65536]; [W_off;W_attn] -> o1[196608];
// W_out -> o2[65536].
// ---------------------------------------------------------------------------
__global__ void cvt_weights_kernel(const float* __restrict__ wv,
                                   const float* __restrict__ woff,
                                   const float* __restrict__ wattn,
                                   const float* __restrict__ wout,
                                   unsigned short* __restrict__ o0,
                                   unsigned short* __restrict__ o1,
                                   unsigned short* __restrict__ o2) {
  int i = blockIdx.x * 256 + threadIdx.x;
  if (i < 65536)        o0[i] = f2bf(wv[i]);
  else if (i < 196608)  o1[i - 65536] = f2bf(woff[i - 65536]);
  else if (i < 262144)  o1[131072 + (i - 196608)] = f2bf(wattn[i - 196608]);
  else if (i < 327680)  o2[i - 262144] = f2bf(wout[i - 262144]);
}

// ---------------------------------------------------------------------------
// bf16-MFMA GEMM with REGISTER DOUBLE-BUFFER (round-3 structure + pipeline):
//   C[m, ch] = sum_k bf16(scale[m]*(A[m,k]+A2[m,k])) * W[ch,k] + bias[ch]
//              (+ R[m,ch])
// 128x128 tile, 4 waves, 4x4 frags of mfma_f32_16x16x32_bf16, BK=32.
// Pipeline: ISSUE(kt+1) raw loads right after the post-store barrier, so the
// vmcnt wait for them lands at the NEXT iteration's STORE — after a full
// ds_read+16-MFMA phase — instead of immediately (round-3 exposed full HBM
// latency every iteration). Raw loads only in ISSUE; A2-add/scale/bf16-pack
// deferred to STORE so no dependent VALU drags the waitcnt earlier.
// Operand roles: W = MFMA A-operand (m=channel), data rows = B-operand.
// D layout: data row = fr, channel = fg*4 + reg -> 8B coalesced stores.
// ---------------------------------------------------------------------------
template <bool BF16_OUT, bool HAS_A2, bool HAS_RES, bool HAS_SCALE>
__global__ __launch_bounds__(256, 3) void gemm_mfma_kernel(
    const float* __restrict__ A, const float* __restrict__ A2,
    const unsigned short* __restrict__ Wbf, const float* __restrict__ bias,
    const float* __restrict__ R, const float* __restrict__ rowscale,
    void* __restrict__ Cv, int M, int N) {
  __shared__ unsigned short As[128 * 40];  // data rows (bf16), pad to 40
  __shared__ unsigned short Bs[128 * 40];  // weight rows (channels)
  const int tid = threadIdx.x;
  const int m0 = blockIdx.x * 128;
  const int n0 = blockIdx.y * 128;
  const int wave = tid >> 6;
  const int lane = tid & 63;
  const int wr = (wave >> 1) * 64;  // row-block within tile
  const int wc = (wave & 1) * 64;   // channel-block within tile
  const int fr = lane & 15;
  const int fg = lane >> 4;

  // staging: thread -> (row 0..127, 16-element half)
  const int sr = tid >> 1;
  const int sc = (tid & 1) * 16;
  const bool a_ok = (m0 + sr) < M;
  const float* Ap = A + (size_t)(m0 + sr) * 256 + sc;
  const float* A2p = HAS_A2 ? (A2 + (size_t)(m0 + sr) * 256 + sc) : nullptr;
  const float ascale = (HAS_SCALE && a_ok) ? rowscale[m0 + sr] : 1.f;
  const unsigned short* Bp = Wbf + (size_t)(n0 + sr) * 256 + sc;
  unsigned short* asw = &As[sr * 40 + sc];
  unsigned short* bsw = &Bs[sr * 40 + sc];

  f32x4 acc[4][4] = {};  // [ct(channel)][rt(row)]

  // register staging buffers (raw, unprocessed)
  float4 ra[4], rt[4];
  uint4 rb0, rb1;

#define GEMM_ISSUE(KT)                                                     \
  {                                                                        \
    _Pragma("unroll") for (int j = 0; j < 4; ++j) {                        \
      ra[j] = a_ok ? *(const float4*)(Ap + (KT) * 32 + 4 * j)              \
                   : make_float4(0.f, 0.f, 0.f, 0.f);                      \
      if (HAS_A2)                                                          \
        rt[j] = a_ok ? *(const float4*)(A2p + (KT) * 32 + 4 * j)           \
                     : make_float4(0.f, 0.f, 0.f, 0.f);                    \
    }                                                                      \
    rb0 = *(const uint4*)(Bp + (KT) * 32);                                 \
    rb1 = *(const uint4*)(Bp + (KT) * 32 + 8);                             \
  }

  GEMM_ISSUE(0);

  for (int kt = 0; kt < 8; ++kt) {
    __syncthreads();  // all waves done reading LDS from previous iteration
    // STORE: process regs -> bf16 -> LDS
    {
      float4 s[4];
#pragma unroll
      for (int j = 0; j < 4; ++j) {
        s[j] = ra[j];
        if (HAS_A2) {
          s[j].x += rt[j].x; s[j].y += rt[j].y;
          s[j].z += rt[j].z; s[j].w += rt[j].w;
        }
        if (HAS_SCALE) {
          s[j].x *= ascale; s[j].y *= ascale;
          s[j].z *= ascale; s[j].w *= ascale;
        }
      }
      uint4 u0, u1;
      u0.x = pack2bf(s[0].x, s[0].y); u0.y = pack2bf(s[0].z, s[0].w);
      u0.z = pack2bf(s[1].x, s[1].y); u0.w = pack2bf(s[1].z, s[1].w);
      u1.x = pack2bf(s[2].x, s[2].y); u1.y = pack2bf(s[2].z, s[2].w);
      u1.z = pack2bf(s[3].x, s[3].y); u1.w = pack2bf(s[3].z, s[3].w);
      *(uint4*)asw = u0;
      *(uint4*)(asw + 8) = u1;
      *(uint4*)bsw = rb0;
      *(uint4*)(bsw + 8) = rb1;
    }
    __syncthreads();

    if (kt < 7) GEMM_ISSUE(kt + 1);  // in flight across the MFMA phase

    short8 wf[4], vf[4];
#pragma unroll
    for (int ct = 0; ct < 4; ++ct)
      wf[ct] = *(const short8*)&Bs[(wc + ct * 16 + fr) * 40 + fg * 8];
#pragma unroll
    for (int rt2 = 0; rt2 < 4; ++rt2)
      vf[rt2] = *(const short8*)&As[(wr + rt2 * 16 + fr) * 40 + fg * 8];
#pragma unroll
    for (int ct = 0; ct < 4; ++ct)
#pragma unroll
      for (int rt2 = 0; rt2 < 4; ++rt2)
        acc[ct][rt2] = __builtin_amdgcn_mfma_f32_16x16x32_bf16(
            wf[ct], vf[rt2], acc[ct][rt2], 0, 0, 0);
  }
#undef GEMM_ISSUE

  // Epilogue: D layout -> data row = fr, channel = fg*4 + reg
#pragma unroll
  for (int rt2 = 0; rt2 < 4; ++rt2) {
    const int m = m0 + wr + rt2 * 16 + fr;
    if (m >= M) continue;
#pragma unroll
    for (int ct = 0; ct < 4; ++ct) {
      const int ch = n0 + wc + ct * 16 + fg * 4;
      float o[4];
#pragma unroll
      for (int r = 0; r < 4; ++r) o[r] = acc[ct][rt2][r] + bias[ch + r];
      if (HAS_RES) {
        const float4 r4 = *(const float4*)&R[(size_t)m * N + ch];
        o[0] += r4.x; o[1] += r4.y; o[2] += r4.z; o[3] += r4.w;
      }
      if (BF16_OUT) {
        ushort4 u;
        u.x = f2bf(o[0]); u.y = f2bf(o[1]); u.z = f2bf(o[2]); u.w = f2bf(o[3]);
        *(ushort4*)((unsigned short*)Cv + (size_t)m * N + ch) = u;
      } else {
        float4 of; of.x = o[0]; of.y = o[1]; of.z = o[2]; of.w = o[3];
        *(float4*)((float*)Cv + (size_t)m * N + ch) = of;
      }
    }
  }
}

// ---------------------------------------------------------------------------
// Sampler v3: one block per (cam, query) pair; 256 threads = 2 sample-groups
// of 128 threads (2 channels each). Group g handles samples [g*16, g*16+16),
// halving each thread's serial gather chain. offlog: [q][768] = [off|logits].
// ---------------------------------------------------------------------------
__global__ __launch_bounds__(256) void sampler3_kernel(
    const unsigned short* __restrict__ v, const float* __restrict__ offlog,
    const float* __restrict__ ref, const unsigned char* __restrict__ mask,
    float* __restrict__ slots) {
  const int pair = blockIdx.x;                 // c * NQ + q
  if (!mask[pair]) return;
  const int c = pair / NQ;
  const int q = pair - c * NQ;
  const int t = threadIdx.x;                   // 0..255

  __shared__ float sx[256], sy[256], sw[256];
  {
    const float Wl[4] = {160.f, 80.f, 40.f, 20.f};
    const float Hl[4] = {92.f, 46.f, 23.f, 12.f};
    const int combo = t;                       // (h,l,p): h=combo>>5
    const int l = (combo >> 3) & 3;
    const int p = combo & 7;
    const int z = p & 3;                       // NP//NZ x NZ reshape
    const float2 rz = ((const float2*)ref)[q * 4 + z];
    const float2 o2 = ((const float2*)offlog)[(size_t)q * 384 + combo];
    sx[combo] = rz.x * Wl[l] + o2.x - 0.5f;
    sy[combo] = rz.y * Hl[l] + o2.y - 0.5f;
    float lg = offlog[(size_t)q * 768 + 512 + combo];
    float mx = lg;
    for (int s = 16; s; s >>= 1) mx = fmaxf(mx, __shfl_xor(mx, s, 32));
    float e = __expf(lg - mx);
    float sm = e;
    for (int s = 16; s; s >>= 1) sm += __shfl_xor(sm, s, 32);
    sw[combo] = e / sm;
  }
  __syncthreads();

  const int WW[4] = {160, 80, 40, 20};
  const int HH[4] = {92, 46, 23, 12};
  const int LS[4] = {0, 14720, 18400, 19320};

  const int tt = t & 127;                      // channel pair
  const int grp = t >> 7;                      // sample group
  const unsigned int* vc =
      (const unsigned int*)(v + (size_t)c * (L_TOT * 256)) + tt;
  const int cbase = (tt >> 4) * 32;
  const int sbase = grp * 16;
  float acc0 = 0.f, acc1 = 0.f;

#pragma unroll
  for (int j = 0; j < 16; ++j) {
    const int s = sbase + j;
    const int lvl = s >> 3;
    const int combo = cbase + s;
    const float x = sx[combo], y = sy[combo], w = sw[combo];
    const float fx0 = floorf(x), fy0 = floorf(y);
    const float fx = x - fx0, fy = y - fy0;
    const int x0 = (int)fx0, y0 = (int)fy0;
    const int Wi = WW[lvl], Hi = HH[lvl];
    const int x0c = min(max(x0, 0), Wi - 1);
    const int x1c = min(max(x0 + 1, 0), Wi - 1);
    const int y0c = min(max(y0, 0), Hi - 1);
    const int y1c = min(max(y0 + 1, 0), Hi - 1);
    const float vx0 = (x0 >= 0 && x0 < Wi) ? 1.f : 0.f;
    const float vx1 = (x0 + 1 >= 0 && x0 + 1 < Wi) ? 1.f : 0.f;
    const float vy0 = (y0 >= 0 && y0 < Hi) ? 1.f : 0.f;
    const float vy1 = (y0 + 1 >= 0 && y0 + 1 < Hi) ? 1.f : 0.f;
    const unsigned int* vl = vc + (size_t)LS[lvl] * 128;
    const unsigned int u00 = vl[(y0c * Wi + x0c) * 128];
    const unsigned int u01 = vl[(y0c * Wi + x1c) * 128];
    const unsigned int u10 = vl[(y1c * Wi + x0c) * 128];
    const unsigned int u11 = vl[(y1c * Wi + x1c) * 128];
    const float w00 = (1.f - fx) * (1.f - fy) * vx0 * vy0 * w;
    const float w01 = fx * (1.f - fy) * vx1 * vy0 * w;
    const float w10 = (1.f - fx) * fy * vx0 * vy1 * w;
    const float w11 = fx * fy * vx1 * vy1 * w;
    acc0 += w00 * bf_lo(u00) + w01 * bf_lo(u01) +
            w10 * bf_lo(u10) + w11 * bf_lo(u11);
    acc1 += w00 * bf_hi(u00) + w01 * bf_hi(u01) +
            w10 * bf_hi(u10) + w11 * bf_hi(u11);
  }
  atomicAdd(&slots[q * 256 + tt * 2], acc0);
  atomicAdd(&slots[q * 256 + tt * 2 + 1], acc1);
}

// ---------------------------------------------------------------------------
extern "C" void kernel_launch(void* const* d_in, const int* in_sizes, int n_in,
                              void* d_out, int out_size, void* d_ws,
                              size_t ws_size, hipStream_t stream) {
  const float* query  = (const float*)d_in[0];
  // d_in[1] = key : unused by the reference forward
  const float* value  = (const float*)d_in[2];
  const float* qpos   = (const float*)d_in[3];
  const float* refpts = (const float*)d_in[4];
  const void*  bmask  = d_in[5];
  const float* W_value = (const float*)d_in[8];
  const float* b_value = (const float*)d_in[9];
  const float* W_off   = (const float*)d_in[10];
  const float* b_off   = (const float*)d_in[11];
  const float* W_attn  = (const float*)d_in[12];
  const float* b_attn  = (const float*)d_in[13];
  const float* W_out   = (const float*)d_in[14];
  const float* b_out   = (const float*)d_in[15];
  float* out = (float*)d_out;

  // workspace layout (~71 MB)
  unsigned short* ws_v = (unsigned short*)d_ws;                    // M_VAL*256 bf16
  unsigned short* ws_wv   = ws_v + (size_t)M_VAL * 256;            // 65536
  unsigned short* ws_wq   = ws_wv + 65536;                         // 196608
  unsigned short* ws_wout = ws_wq + 196608;                        // 65536
  float* ws_offlog = (float*)(ws_wout + 65536);                    // NQ*768
  float* ws_slots  = ws_offlog + (size_t)NQ * 768;                 // NQ*256
  float* ws_invcnt = ws_slots + (size_t)NQ * 256;                  // NQ
  float* ws_bcat   = ws_invcnt + NQ;                               // 768
  unsigned char* ws_mask = (unsigned char*)(ws_bcat + 768);        // NCAMS*NQ

  canon_mask_kernel<<<60, 256, 0, stream>>>(bmask, ws_mask, ws_invcnt,
                                            b_off, b_attn, ws_bcat);
  cvt_weights_kernel<<<1280, 256, 0, stream>>>(
      W_value, W_off, W_attn, W_out, ws_wv, ws_wq, ws_wout);
  hipMemsetAsync(ws_slots, 0, (size_t)NQ * 256 * sizeof(float), stream);

  // v = value @ W_value^T + b_value   (117360 x 256), bf16 out
  gemm_mfma_kernel<true, false, false, false><<<dim3(917, 2), 256, 0, stream>>>(
      value, nullptr, ws_wv, b_value, nullptr, nullptr, (void*)ws_v,
      M_VAL, 256);

  // [off | logits] = (q+qpos) @ [W_off;W_attn]^T + bcat   (2500 x 768)
  gemm_mfma_kernel<false, true, false, false><<<dim3(20, 6), 256, 0, stream>>>(
      query, qpos, ws_wq, ws_bcat, nullptr, nullptr, (void*)ws_offlog,
      NQ, 768);

  sampler3_kernel<<<NCAMS * NQ, 256, 0, stream>>>(
      ws_v, ws_offlog, refpts, ws_mask, ws_slots);

  // out = (slots/cnt) @ W_out^T + b_out + query   (2500 x 256)
  gemm_mfma_kernel<false, false, true, true><<<dim3(20, 2), 256, 0, stream>>>(
      ws_slots, nullptr, ws_wout, b_out, query, ws_invcnt, (void*)out,
      NQ, 256);
}